// Round 1
// baseline (979.279 us; speedup 1.0000x reference)
//
#include <hip/hip_runtime.h>
#include <math.h>

#define NN 50000
#define NE 400000

__device__ __forceinline__ float silu_f(float x) {
    return x * (1.0f / (1.0f + __expf(-x)));
}

#define FMA16(ACC, A, W) do { \
    ACC[0][0] += A.x*W.x; ACC[0][1] += A.x*W.y; ACC[0][2] += A.x*W.z; ACC[0][3] += A.x*W.w; \
    ACC[1][0] += A.y*W.x; ACC[1][1] += A.y*W.y; ACC[1][2] += A.y*W.z; ACC[1][3] += A.y*W.w; \
    ACC[2][0] += A.z*W.x; ACC[2][1] += A.z*W.y; ACC[2][2] += A.z*W.z; ACC[2][3] += A.z*W.w; \
    ACC[3][0] += A.w*W.x; ACC[3][1] += A.w*W.y; ACC[3][2] += A.w*W.z; ACC[3][3] += A.w*W.w; \
} while (0)

// ---------------- zero workspace ----------------
__global__ void zero_kernel(float4* __restrict__ p, int n4) {
    int i = blockIdx.x * blockDim.x + threadIdx.x;
    int st = gridDim.x * blockDim.x;
    for (; i < n4; i += st) p[i] = make_float4(0.f, 0.f, 0.f, 0.f);
}

// ---------------- edge pipeline ----------------
// 32 edges / block, 256 threads. Fused: gather -> MLP1(K=320) -> MLP2(K=128)
// -> scatter-add messages -> coord MLP -> scatter-add coord updates.
__global__ __launch_bounds__(256, 2) void edge_kernel(
    const float* __restrict__ node_feat,
    const float* __restrict__ edge_attr,
    const float* __restrict__ coords,
    const int*   __restrict__ edge_index,
    const float* __restrict__ We1, const float* __restrict__ be1,
    const float* __restrict__ We2, const float* __restrict__ be2,
    const float* __restrict__ Wc1, const float* __restrict__ bc1,
    const float* __restrict__ Wc2, const float* __restrict__ bc2,
    float* __restrict__ aggr, float* __restrict__ coord_acc)
{
    __shared__ float As[32][36];        // A chunk, transposed: As[k][e]
    __shared__ float Ws[32][128];       // weight chunk: Ws[k][n]
    __shared__ float H1t[128][36];      // h1 transposed; later aliased as C1t[64][36]
    __shared__ float H2t[128][36];      // h2 (edge_message) transposed
    __shared__ int   sSrc[32], sDst[32];

    const int tid = threadIdx.x;
    const int eb  = blockIdx.x * 32;

    if (tid < 32) {
        sSrc[tid] = edge_index[eb + tid];
        sDst[tid] = edge_index[NE + eb + tid];
    }
    __syncthreads();

    const int tx = tid & 31;        // col group (4 cols)
    const int ty = tid >> 5;        // edge group (4 edges)
    const int n0 = tx * 4;
    const int e0 = ty * 4;
    const int le = tid >> 3;        // staging: edge index
    const int kq = (tid & 7) * 4;   // staging: k offset

    // ===== MLP1: h1 = silu(A @ We1 + be1), A = [x_src | x_dst | edge_attr], K=320
    float acc[4][4];
    #pragma unroll
    for (int i = 0; i < 4; ++i)
        #pragma unroll
        for (int j = 0; j < 4; ++j) acc[i][j] = 0.f;

    for (int kc = 0; kc < 10; ++kc) {
        {   // stage A chunk (gathered, transposed). Chunk boundaries (128,256) are /32.
            const int gk = kc * 32 + kq;
            const float* sp;
            if      (gk < 128) sp = node_feat + (size_t)sSrc[le] * 128 + gk;
            else if (gk < 256) sp = node_feat + (size_t)sDst[le] * 128 + (gk - 128);
            else               sp = edge_attr + (size_t)(eb + le) * 64 + (gk - 256);
            const float4 v = *(const float4*)sp;
            As[kq + 0][le] = v.x; As[kq + 1][le] = v.y;
            As[kq + 2][le] = v.z; As[kq + 3][le] = v.w;
        }
        #pragma unroll
        for (int j = 0; j < 4; ++j) {   // stage We1 chunk [32][128]
            const int flat = (tid + j * 256) * 4;
            const int k = flat >> 7, c = flat & 127;
            *(float4*)&Ws[k][c] = *(const float4*)&We1[(size_t)(kc * 32 + k) * 128 + c];
        }
        __syncthreads();
        #pragma unroll 8
        for (int k = 0; k < 32; ++k) {
            const float4 a = *(const float4*)&As[k][e0];
            const float4 w = *(const float4*)&Ws[k][n0];
            FMA16(acc, a, w);
        }
        __syncthreads();
    }
    {   // epilogue: bias + silu -> H1t
        const float4 b = *(const float4*)&be1[n0];
        const float bb[4] = {b.x, b.y, b.z, b.w};
        #pragma unroll
        for (int j = 0; j < 4; ++j) {
            float4 h;
            h.x = silu_f(acc[0][j] + bb[j]);
            h.y = silu_f(acc[1][j] + bb[j]);
            h.z = silu_f(acc[2][j] + bb[j]);
            h.w = silu_f(acc[3][j] + bb[j]);
            *(float4*)&H1t[n0 + j][e0] = h;
        }
    }

    // ===== MLP2: h2 = silu(h1 @ We2 + be2), K=128
    float acc2[4][4];
    #pragma unroll
    for (int i = 0; i < 4; ++i)
        #pragma unroll
        for (int j = 0; j < 4; ++j) acc2[i][j] = 0.f;

    for (int kc = 0; kc < 4; ++kc) {
        #pragma unroll
        for (int j = 0; j < 4; ++j) {
            const int flat = (tid + j * 256) * 4;
            const int k = flat >> 7, c = flat & 127;
            *(float4*)&Ws[k][c] = *(const float4*)&We2[(size_t)(kc * 32 + k) * 128 + c];
        }
        __syncthreads();
        #pragma unroll 8
        for (int k = 0; k < 32; ++k) {
            const float4 a = *(const float4*)&H1t[kc * 32 + k][e0];
            const float4 w = *(const float4*)&Ws[k][n0];
            FMA16(acc2, a, w);
        }
        __syncthreads();
    }
    {   // epilogue -> H2t
        const float4 b = *(const float4*)&be2[n0];
        const float bb[4] = {b.x, b.y, b.z, b.w};
        #pragma unroll
        for (int j = 0; j < 4; ++j) {
            float4 h;
            h.x = silu_f(acc2[0][j] + bb[j]);
            h.y = silu_f(acc2[1][j] + bb[j]);
            h.z = silu_f(acc2[2][j] + bb[j]);
            h.w = silu_f(acc2[3][j] + bb[j]);
            *(float4*)&H2t[n0 + j][e0] = h;
        }
    }
    __syncthreads();

    // ===== scatter edge messages: aggr[dst] += h2  (coalesced over c within wave)
    #pragma unroll
    for (int i = 0; i < 16; ++i) {
        const int idx = i * 256 + tid;
        const int e = idx >> 7;
        const int c = idx & 127;
        atomicAdd(&aggr[(size_t)sDst[e] * 128 + c], H2t[c][e]);
    }

    // ===== coord MLP1: c1 = silu(h2 @ Wc1 + bc1), K=128, Nc=64
    const int n0c = tx * 2;
    float acc3[4][2];
    #pragma unroll
    for (int i = 0; i < 4; ++i) { acc3[i][0] = 0.f; acc3[i][1] = 0.f; }

    for (int kc = 0; kc < 4; ++kc) {
        #pragma unroll
        for (int j = 0; j < 2; ++j) {   // stage Wc1 chunk [32][64]
            const int flat = (tid + j * 256) * 4;
            const int k = flat >> 6, c = flat & 63;
            *(float4*)&Ws[k][c] = *(const float4*)&Wc1[(size_t)(kc * 32 + k) * 64 + c];
        }
        __syncthreads();
        #pragma unroll 8
        for (int k = 0; k < 32; ++k) {
            const float4 a = *(const float4*)&H2t[kc * 32 + k][e0];
            const float w0 = Ws[k][n0c], w1 = Ws[k][n0c + 1];
            acc3[0][0] += a.x * w0; acc3[0][1] += a.x * w1;
            acc3[1][0] += a.y * w0; acc3[1][1] += a.y * w1;
            acc3[2][0] += a.z * w0; acc3[2][1] += a.z * w1;
            acc3[3][0] += a.w * w0; acc3[3][1] += a.w * w1;
        }
        __syncthreads();
    }
    float (*C1t)[36] = H1t;   // h1 is dead; reuse its LDS
    {
        #pragma unroll
        for (int j = 0; j < 2; ++j) {
            const float b = bc1[n0c + j];
            float4 h;
            h.x = silu_f(acc3[0][j] + b);
            h.y = silu_f(acc3[1][j] + b);
            h.z = silu_f(acc3[2][j] + b);
            h.w = silu_f(acc3[3][j] + b);
            *(float4*)&C1t[n0c + j][e0] = h;
        }
    }
    __syncthreads();

    // ===== coord_w = c1 @ Wc2 + bc2; equivariant update scatter
    if (tid < 32) {
        const int e = tid;
        float w = bc2[0];
        #pragma unroll
        for (int k = 0; k < 64; ++k) w += C1t[k][e] * Wc2[k];
        const int s = sSrc[e], d = sDst[e];
        const float dx = coords[3 * s + 0] - coords[3 * d + 0];
        const float dy = coords[3 * s + 1] - coords[3 * d + 1];
        const float dz = coords[3 * s + 2] - coords[3 * d + 2];
        const float inv = w / (sqrtf(dx * dx + dy * dy + dz * dz) + 1e-8f);
        atomicAdd(&coord_acc[3 * d + 0], dx * inv);
        atomicAdd(&coord_acc[3 * d + 1], dy * inv);
        atomicAdd(&coord_acc[3 * d + 2], dz * inv);
    }
}

// ---------------- node update ----------------
// 32 nodes / block, 256 threads. concat(node_feat, aggr) -> MLP -> residual; coords add.
__global__ __launch_bounds__(256, 4) void node_kernel(
    const float* __restrict__ node_feat,
    const float* __restrict__ coords,
    const float* __restrict__ Wn1, const float* __restrict__ bn1,
    const float* __restrict__ Wn2, const float* __restrict__ bn2,
    const float* __restrict__ aggr, const float* __restrict__ coord_acc,
    float* __restrict__ out)
{
    __shared__ float As[32][36];
    __shared__ float Ws[32][128];
    __shared__ float H1t[128][36];

    const int tid = threadIdx.x;
    const int nb  = blockIdx.x * 32;
    const int tx = tid & 31, ty = tid >> 5;
    const int n0 = tx * 4, r0 = ty * 4;
    const int lr = tid >> 3, kq = (tid & 7) * 4;
    const int grow = min(nb + lr, NN - 1);   // clamp; invalid rows masked at store

    // MLP1: K=256 ([node_feat | aggr])
    float acc[4][4];
    #pragma unroll
    for (int i = 0; i < 4; ++i)
        #pragma unroll
        for (int j = 0; j < 4; ++j) acc[i][j] = 0.f;

    for (int kc = 0; kc < 8; ++kc) {
        {
            const int gk = kc * 32 + kq;
            const float* sp = (gk < 128) ? node_feat + (size_t)grow * 128 + gk
                                         : aggr + (size_t)grow * 128 + (gk - 128);
            const float4 v = *(const float4*)sp;
            As[kq + 0][lr] = v.x; As[kq + 1][lr] = v.y;
            As[kq + 2][lr] = v.z; As[kq + 3][lr] = v.w;
        }
        #pragma unroll
        for (int j = 0; j < 4; ++j) {
            const int flat = (tid + j * 256) * 4;
            const int k = flat >> 7, c = flat & 127;
            *(float4*)&Ws[k][c] = *(const float4*)&Wn1[(size_t)(kc * 32 + k) * 128 + c];
        }
        __syncthreads();
        #pragma unroll 8
        for (int k = 0; k < 32; ++k) {
            const float4 a = *(const float4*)&As[k][r0];
            const float4 w = *(const float4*)&Ws[k][n0];
            FMA16(acc, a, w);
        }
        __syncthreads();
    }
    {
        const float4 b = *(const float4*)&bn1[n0];
        const float bb[4] = {b.x, b.y, b.z, b.w};
        #pragma unroll
        for (int j = 0; j < 4; ++j) {
            float4 h;
            h.x = silu_f(acc[0][j] + bb[j]);
            h.y = silu_f(acc[1][j] + bb[j]);
            h.z = silu_f(acc[2][j] + bb[j]);
            h.w = silu_f(acc[3][j] + bb[j]);
            *(float4*)&H1t[n0 + j][r0] = h;
        }
    }

    // MLP2: K=128, then residual
    float acc2[4][4];
    #pragma unroll
    for (int i = 0; i < 4; ++i)
        #pragma unroll
        for (int j = 0; j < 4; ++j) acc2[i][j] = 0.f;

    for (int kc = 0; kc < 4; ++kc) {
        #pragma unroll
        for (int j = 0; j < 4; ++j) {
            const int flat = (tid + j * 256) * 4;
            const int k = flat >> 7, c = flat & 127;
            *(float4*)&Ws[k][c] = *(const float4*)&Wn2[(size_t)(kc * 32 + k) * 128 + c];
        }
        __syncthreads();
        #pragma unroll 8
        for (int k = 0; k < 32; ++k) {
            const float4 a = *(const float4*)&H1t[kc * 32 + k][r0];
            const float4 w = *(const float4*)&Ws[k][n0];
            FMA16(acc2, a, w);
        }
        __syncthreads();
    }
    {
        const float4 b = *(const float4*)&bn2[n0];
        const float bb[4] = {b.x, b.y, b.z, b.w};
        #pragma unroll
        for (int i = 0; i < 4; ++i) {
            const int row = nb + r0 + i;
            if (row < NN) {
                const float4 nf = *(const float4*)&node_feat[(size_t)row * 128 + n0];
                float4 o;
                o.x = acc2[i][0] + bb[0] + nf.x;
                o.y = acc2[i][1] + bb[1] + nf.y;
                o.z = acc2[i][2] + bb[2] + nf.z;
                o.w = acc2[i][3] + bb[3] + nf.w;
                *(float4*)&out[(size_t)row * 128 + n0] = o;
            }
        }
    }

    // coords epilogue
    if (tid < 96) {
        const int n = nb + tid / 3;
        const int j = tid % 3;
        if (n < NN) {
            out[(size_t)NN * 128 + 3 * n + j] = coords[3 * n + j] + coord_acc[3 * n + j];
        }
    }
}

extern "C" void kernel_launch(void* const* d_in, const int* in_sizes, int n_in,
                              void* d_out, int out_size, void* d_ws, size_t ws_size,
                              hipStream_t stream)
{
    const float* node_feat  = (const float*)d_in[0];
    const float* edge_attr  = (const float*)d_in[1];
    const float* coords     = (const float*)d_in[2];
    const int*   edge_index = (const int*)d_in[3];
    const float* We1 = (const float*)d_in[4];
    const float* be1 = (const float*)d_in[5];
    const float* We2 = (const float*)d_in[6];
    const float* be2 = (const float*)d_in[7];
    const float* Wn1 = (const float*)d_in[8];
    const float* bn1 = (const float*)d_in[9];
    const float* Wn2 = (const float*)d_in[10];
    const float* bn2 = (const float*)d_in[11];
    const float* Wc1 = (const float*)d_in[12];
    const float* bc1 = (const float*)d_in[13];
    const float* Wc2 = (const float*)d_in[14];
    const float* bc2 = (const float*)d_in[15];

    float* out       = (float*)d_out;
    float* aggr      = (float*)d_ws;                       // [NN,128]
    float* coord_acc = aggr + (size_t)NN * 128;            // [NN,3]

    const int n4 = (NN * 128 + NN * 3) / 4;                // re-zero accumulators every call
    zero_kernel<<<2048, 256, 0, stream>>>((float4*)d_ws, n4);

    edge_kernel<<<NE / 32, 256, 0, stream>>>(
        node_feat, edge_attr, coords, edge_index,
        We1, be1, We2, be2, Wc1, bc1, Wc2, bc2,
        aggr, coord_acc);

    node_kernel<<<(NN + 31) / 32, 256, 0, stream>>>(
        node_feat, coords, Wn1, bn1, Wn2, bn2,
        aggr, coord_acc, out);
}

// Round 2
// 944.708 us; speedup vs baseline: 1.0366x; 1.0366x over previous
//
#include <hip/hip_runtime.h>
#include <math.h>

#define NN 50000
#define NE 400000

__device__ __forceinline__ float silu_f(float x) {
    return x * (1.0f / (1.0f + __expf(-x)));
}

#define FMA16(ACC, A, W) do { \
    ACC[0][0] += A.x*W.x; ACC[0][1] += A.x*W.y; ACC[0][2] += A.x*W.z; ACC[0][3] += A.x*W.w; \
    ACC[1][0] += A.y*W.x; ACC[1][1] += A.y*W.y; ACC[1][2] += A.y*W.z; ACC[1][3] += A.y*W.w; \
    ACC[2][0] += A.z*W.x; ACC[2][1] += A.z*W.y; ACC[2][2] += A.z*W.z; ACC[2][3] += A.z*W.w; \
    ACC[3][0] += A.w*W.x; ACC[3][1] += A.w*W.y; ACC[3][2] += A.w*W.z; ACC[3][3] += A.w*W.w; \
} while (0)

// ---------------- zero workspace ----------------
__global__ void zero_kernel(float4* __restrict__ p, int n4) {
    int i = blockIdx.x * blockDim.x + threadIdx.x;
    int st = gridDim.x * blockDim.x;
    for (; i < n4; i += st) p[i] = make_float4(0.f, 0.f, 0.f, 0.f);
}

// ---------------- edge pipeline ----------------
// 32 edges / block, 256 threads. h1/h2 live in registers (4 edges x 4 cols per
// thread); the next GEMM's A-chunk is staged through the small As buffer from
// registers, one 32-k chunk at a time. LDS ~21 KB -> 4+ blocks/CU.
__global__ __launch_bounds__(256, 4) void edge_kernel(
    const float* __restrict__ node_feat,
    const float* __restrict__ edge_attr,
    const float* __restrict__ coords,
    const int*   __restrict__ edge_index,
    const float* __restrict__ We1, const float* __restrict__ be1,
    const float* __restrict__ We2, const float* __restrict__ be2,
    const float* __restrict__ Wc1, const float* __restrict__ bc1,
    const float* __restrict__ Wc2, const float* __restrict__ bc2,
    float* __restrict__ aggr, float* __restrict__ coord_acc)
{
    __shared__ float As[32][36];        // A chunk, transposed: As[k][e]
    __shared__ float Ws[32][128];       // weight chunk: Ws[k][n]
    __shared__ int   sSrc[32], sDst[32];

    const int tid = threadIdx.x;
    const int eb  = blockIdx.x * 32;

    if (tid < 32) {
        sSrc[tid] = edge_index[eb + tid];
        sDst[tid] = edge_index[NE + eb + tid];
    }
    __syncthreads();

    const int tx = tid & 31;        // col group (4 cols)
    const int ty = tid >> 5;        // edge group (4 edges)
    const int n0 = tx * 4;
    const int e0 = ty * 4;
    const int le = tid >> 3;        // staging: edge index
    const int kq = (tid & 7) * 4;   // staging: k offset

    // ===== MLP1: h1 = silu(A @ We1 + be1), A = [x_src | x_dst | edge_attr], K=320
    float acc[4][4];
    #pragma unroll
    for (int i = 0; i < 4; ++i)
        #pragma unroll
        for (int j = 0; j < 4; ++j) acc[i][j] = 0.f;

    for (int kc = 0; kc < 10; ++kc) {
        {   // stage A chunk (gathered, transposed). Chunk boundaries (128,256) are /32.
            const int gk = kc * 32 + kq;
            const float* sp;
            if      (gk < 128) sp = node_feat + (size_t)sSrc[le] * 128 + gk;
            else if (gk < 256) sp = node_feat + (size_t)sDst[le] * 128 + (gk - 128);
            else               sp = edge_attr + (size_t)(eb + le) * 64 + (gk - 256);
            const float4 v = *(const float4*)sp;
            As[kq + 0][le] = v.x; As[kq + 1][le] = v.y;
            As[kq + 2][le] = v.z; As[kq + 3][le] = v.w;
        }
        #pragma unroll
        for (int j = 0; j < 4; ++j) {   // stage We1 chunk [32][128]
            const int flat = (tid + j * 256) * 4;
            const int k = flat >> 7, c = flat & 127;
            *(float4*)&Ws[k][c] = *(const float4*)&We1[(size_t)(kc * 32 + k) * 128 + c];
        }
        __syncthreads();
        #pragma unroll 8
        for (int k = 0; k < 32; ++k) {
            const float4 a = *(const float4*)&As[k][e0];
            const float4 w = *(const float4*)&Ws[k][n0];
            FMA16(acc, a, w);
        }
        __syncthreads();
    }

    // h1 -> registers (bias + silu)
    float h1r[4][4];
    {
        const float4 b = *(const float4*)&be1[n0];
        const float bb[4] = {b.x, b.y, b.z, b.w};
        #pragma unroll
        for (int i = 0; i < 4; ++i)
            #pragma unroll
            for (int j = 0; j < 4; ++j) h1r[i][j] = silu_f(acc[i][j] + bb[j]);
    }

    // ===== MLP2: h2 = silu(h1 @ We2 + be2), K=128; A-chunk staged from registers
    float acc2[4][4];
    #pragma unroll
    for (int i = 0; i < 4; ++i)
        #pragma unroll
        for (int j = 0; j < 4; ++j) acc2[i][j] = 0.f;

    #pragma unroll
    for (int kc = 0; kc < 4; ++kc) {
        #pragma unroll
        for (int j = 0; j < 4; ++j) {   // stage We2 chunk
            const int flat = (tid + j * 256) * 4;
            const int k = flat >> 7, c = flat & 127;
            *(float4*)&Ws[k][c] = *(const float4*)&We2[(size_t)(kc * 32 + k) * 128 + c];
        }
        if ((tx >> 3) == kc) {          // this tx group owns cols [32kc, 32kc+32)
            #pragma unroll
            for (int j = 0; j < 4; ++j) {
                *(float4*)&As[(tx & 7) * 4 + j][e0] =
                    make_float4(h1r[0][j], h1r[1][j], h1r[2][j], h1r[3][j]);
            }
        }
        __syncthreads();
        #pragma unroll 8
        for (int k = 0; k < 32; ++k) {
            const float4 a = *(const float4*)&As[k][e0];
            const float4 w = *(const float4*)&Ws[k][n0];
            FMA16(acc2, a, w);
        }
        __syncthreads();
    }

    // h2 -> registers (bias + silu)
    float h2r[4][4];
    {
        const float4 b = *(const float4*)&be2[n0];
        const float bb[4] = {b.x, b.y, b.z, b.w};
        #pragma unroll
        for (int i = 0; i < 4; ++i)
            #pragma unroll
            for (int j = 0; j < 4; ++j) h2r[i][j] = silu_f(acc2[i][j] + bb[j]);
    }

    // ===== scatter edge messages from registers: aggr[dst[e]] += h2[e]
    #pragma unroll
    for (int i = 0; i < 4; ++i) {
        float* base = aggr + (size_t)sDst[e0 + i] * 128 + n0;
        #pragma unroll
        for (int j = 0; j < 4; ++j) atomicAdd(base + j, h2r[i][j]);
    }

    // ===== coord MLP1: c1 = silu(h2 @ Wc1 + bc1), K=128, Nc=64
    const int n0c = tx * 2;
    float acc3[4][2];
    #pragma unroll
    for (int i = 0; i < 4; ++i) { acc3[i][0] = 0.f; acc3[i][1] = 0.f; }

    #pragma unroll
    for (int kc = 0; kc < 4; ++kc) {
        #pragma unroll
        for (int j = 0; j < 2; ++j) {   // stage Wc1 chunk [32][64]
            const int flat = (tid + j * 256) * 4;
            const int k = flat >> 6, c = flat & 63;
            *(float4*)&Ws[k][c] = *(const float4*)&Wc1[(size_t)(kc * 32 + k) * 64 + c];
        }
        if ((tx >> 3) == kc) {          // stage h2 chunk from registers
            #pragma unroll
            for (int j = 0; j < 4; ++j) {
                *(float4*)&As[(tx & 7) * 4 + j][e0] =
                    make_float4(h2r[0][j], h2r[1][j], h2r[2][j], h2r[3][j]);
            }
        }
        __syncthreads();
        #pragma unroll 8
        for (int k = 0; k < 32; ++k) {
            const float4 a = *(const float4*)&As[k][e0];
            const float2 w = *(const float2*)&Ws[k][n0c];
            acc3[0][0] += a.x * w.x; acc3[0][1] += a.x * w.y;
            acc3[1][0] += a.y * w.x; acc3[1][1] += a.y * w.y;
            acc3[2][0] += a.z * w.x; acc3[2][1] += a.z * w.y;
            acc3[3][0] += a.w * w.x; acc3[3][1] += a.w * w.y;
        }
        __syncthreads();
    }

    // ===== coord_w[e] = silu(c1) @ Wc2 + bc2 via shuffle butterfly over tx
    {
        const float2 bcv = *(const float2*)&bc1[n0c];
        const float2 wcv = *(const float2*)&Wc2[n0c];
        float part[4];
        #pragma unroll
        for (int i = 0; i < 4; ++i) {
            part[i] = silu_f(acc3[i][0] + bcv.x) * wcv.x
                    + silu_f(acc3[i][1] + bcv.y) * wcv.y;
        }
        #pragma unroll
        for (int m = 1; m <= 16; m <<= 1) {
            #pragma unroll
            for (int i = 0; i < 4; ++i) part[i] += __shfl_xor(part[i], m);
        }
        if (tx == 0) {
            const float b2 = bc2[0];
            #pragma unroll
            for (int i = 0; i < 4; ++i) {
                const int e = e0 + i;
                const int s = sSrc[e], d = sDst[e];
                const float dx = coords[3 * s + 0] - coords[3 * d + 0];
                const float dy = coords[3 * s + 1] - coords[3 * d + 1];
                const float dz = coords[3 * s + 2] - coords[3 * d + 2];
                const float w  = part[i] + b2;
                const float inv = w / (sqrtf(dx * dx + dy * dy + dz * dz) + 1e-8f);
                atomicAdd(&coord_acc[3 * d + 0], dx * inv);
                atomicAdd(&coord_acc[3 * d + 1], dy * inv);
                atomicAdd(&coord_acc[3 * d + 2], dz * inv);
            }
        }
    }
}

// ---------------- node update ----------------
// 32 nodes / block, 256 threads. concat(node_feat, aggr) -> MLP -> residual; coords add.
__global__ __launch_bounds__(256, 4) void node_kernel(
    const float* __restrict__ node_feat,
    const float* __restrict__ coords,
    const float* __restrict__ Wn1, const float* __restrict__ bn1,
    const float* __restrict__ Wn2, const float* __restrict__ bn2,
    const float* __restrict__ aggr, const float* __restrict__ coord_acc,
    float* __restrict__ out)
{
    __shared__ float As[32][36];
    __shared__ float Ws[32][128];

    const int tid = threadIdx.x;
    const int nb  = blockIdx.x * 32;
    const int tx = tid & 31, ty = tid >> 5;
    const int n0 = tx * 4, r0 = ty * 4;
    const int lr = tid >> 3, kq = (tid & 7) * 4;
    const int grow = min(nb + lr, NN - 1);   // clamp; invalid rows masked at store

    // MLP1: K=256 ([node_feat | aggr])
    float acc[4][4];
    #pragma unroll
    for (int i = 0; i < 4; ++i)
        #pragma unroll
        for (int j = 0; j < 4; ++j) acc[i][j] = 0.f;

    for (int kc = 0; kc < 8; ++kc) {
        {
            const int gk = kc * 32 + kq;
            const float* sp = (gk < 128) ? node_feat + (size_t)grow * 128 + gk
                                         : aggr + (size_t)grow * 128 + (gk - 128);
            const float4 v = *(const float4*)sp;
            As[kq + 0][lr] = v.x; As[kq + 1][lr] = v.y;
            As[kq + 2][lr] = v.z; As[kq + 3][lr] = v.w;
        }
        #pragma unroll
        for (int j = 0; j < 4; ++j) {
            const int flat = (tid + j * 256) * 4;
            const int k = flat >> 7, c = flat & 127;
            *(float4*)&Ws[k][c] = *(const float4*)&Wn1[(size_t)(kc * 32 + k) * 128 + c];
        }
        __syncthreads();
        #pragma unroll 8
        for (int k = 0; k < 32; ++k) {
            const float4 a = *(const float4*)&As[k][r0];
            const float4 w = *(const float4*)&Ws[k][n0];
            FMA16(acc, a, w);
        }
        __syncthreads();
    }

    // h1 -> registers
    float h1r[4][4];
    {
        const float4 b = *(const float4*)&bn1[n0];
        const float bb[4] = {b.x, b.y, b.z, b.w};
        #pragma unroll
        for (int i = 0; i < 4; ++i)
            #pragma unroll
            for (int j = 0; j < 4; ++j) h1r[i][j] = silu_f(acc[i][j] + bb[j]);
    }

    // MLP2: K=128, A-chunk staged from registers; then residual
    float acc2[4][4];
    #pragma unroll
    for (int i = 0; i < 4; ++i)
        #pragma unroll
        for (int j = 0; j < 4; ++j) acc2[i][j] = 0.f;

    #pragma unroll
    for (int kc = 0; kc < 4; ++kc) {
        #pragma unroll
        for (int j = 0; j < 4; ++j) {
            const int flat = (tid + j * 256) * 4;
            const int k = flat >> 7, c = flat & 127;
            *(float4*)&Ws[k][c] = *(const float4*)&Wn2[(size_t)(kc * 32 + k) * 128 + c];
        }
        if ((tx >> 3) == kc) {
            #pragma unroll
            for (int j = 0; j < 4; ++j) {
                *(float4*)&As[(tx & 7) * 4 + j][r0] =
                    make_float4(h1r[0][j], h1r[1][j], h1r[2][j], h1r[3][j]);
            }
        }
        __syncthreads();
        #pragma unroll 8
        for (int k = 0; k < 32; ++k) {
            const float4 a = *(const float4*)&As[k][r0];
            const float4 w = *(const float4*)&Ws[k][n0];
            FMA16(acc2, a, w);
        }
        __syncthreads();
    }
    {
        const float4 b = *(const float4*)&bn2[n0];
        const float bb[4] = {b.x, b.y, b.z, b.w};
        #pragma unroll
        for (int i = 0; i < 4; ++i) {
            const int row = nb + r0 + i;
            if (row < NN) {
                const float4 nf = *(const float4*)&node_feat[(size_t)row * 128 + n0];
                float4 o;
                o.x = acc2[i][0] + bb[0] + nf.x;
                o.y = acc2[i][1] + bb[1] + nf.y;
                o.z = acc2[i][2] + bb[2] + nf.z;
                o.w = acc2[i][3] + bb[3] + nf.w;
                *(float4*)&out[(size_t)row * 128 + n0] = o;
            }
        }
    }

    // coords epilogue
    if (tid < 96) {
        const int n = nb + tid / 3;
        const int j = tid % 3;
        if (n < NN) {
            out[(size_t)NN * 128 + 3 * n + j] = coords[3 * n + j] + coord_acc[3 * n + j];
        }
    }
}

extern "C" void kernel_launch(void* const* d_in, const int* in_sizes, int n_in,
                              void* d_out, int out_size, void* d_ws, size_t ws_size,
                              hipStream_t stream)
{
    const float* node_feat  = (const float*)d_in[0];
    const float* edge_attr  = (const float*)d_in[1];
    const float* coords     = (const float*)d_in[2];
    const int*   edge_index = (const int*)d_in[3];
    const float* We1 = (const float*)d_in[4];
    const float* be1 = (const float*)d_in[5];
    const float* We2 = (const float*)d_in[6];
    const float* be2 = (const float*)d_in[7];
    const float* Wn1 = (const float*)d_in[8];
    const float* bn1 = (const float*)d_in[9];
    const float* Wn2 = (const float*)d_in[10];
    const float* bn2 = (const float*)d_in[11];
    const float* Wc1 = (const float*)d_in[12];
    const float* bc1 = (const float*)d_in[13];
    const float* Wc2 = (const float*)d_in[14];
    const float* bc2 = (const float*)d_in[15];

    float* out       = (float*)d_out;
    float* aggr      = (float*)d_ws;                       // [NN,128]
    float* coord_acc = aggr + (size_t)NN * 128;            // [NN,3]

    const int n4 = (NN * 128 + NN * 3) / 4;                // re-zero accumulators every call
    zero_kernel<<<2048, 256, 0, stream>>>((float4*)d_ws, n4);

    edge_kernel<<<NE / 32, 256, 0, stream>>>(
        node_feat, edge_attr, coords, edge_index,
        We1, be1, We2, be2, Wc1, bc1, Wc2, bc2,
        aggr, coord_acc);

    node_kernel<<<(NN + 31) / 32, 256, 0, stream>>>(
        node_feat, coords, Wn1, bn1, Wn2, bn2,
        aggr, coord_acc, out);
}

// Round 3
// 442.453 us; speedup vs baseline: 2.2133x; 2.1352x over previous
//
#include <hip/hip_runtime.h>
#include <hip/hip_bf16.h>
#include <math.h>

#define NN 50000
#define NE 400000

typedef __attribute__((ext_vector_type(8))) short short8;
typedef __attribute__((ext_vector_type(4))) float f32x4;

// bf16 weight workspace layout (element offsets)
#define OFF_WE1T 0           // [128][320]
#define OFF_WE2T 40960       // [128][128]
#define OFF_WN1T 57344       // [128][256]
#define OFF_WN2T 90112       // [128][128]
#define OFF_WC1T 106496      // [64][128]
#define W_TOTAL  114688

__device__ __forceinline__ float silu_f(float x) {
    return x * (1.0f / (1.0f + __expf(-x)));
}
__device__ __forceinline__ short f2bf(float f) {
    __hip_bfloat16 b = __float2bfloat16(f);
    return *reinterpret_cast<short*>(&b);
}
__device__ __forceinline__ short8 cvt8(float4 a, float4 b) {
    short8 r;
    r[0] = f2bf(a.x); r[1] = f2bf(a.y); r[2] = f2bf(a.z); r[3] = f2bf(a.w);
    r[4] = f2bf(b.x); r[5] = f2bf(b.y); r[6] = f2bf(b.z); r[7] = f2bf(b.w);
    return r;
}

// ---------------- zero aggr/coord accumulators ----------------
__global__ void zero_kernel(float4* __restrict__ p, int n4) {
    int i = blockIdx.x * blockDim.x + threadIdx.x;
    int st = gridDim.x * blockDim.x;
    for (; i < n4; i += st) p[i] = make_float4(0.f, 0.f, 0.f, 0.f);
}

// ---------------- weight prep: fp32 [K][N] -> bf16 transposed [N][K] ----------------
__global__ __launch_bounds__(256) void prep_kernel(
    const float* __restrict__ We1, const float* __restrict__ We2,
    const float* __restrict__ Wn1, const float* __restrict__ Wn2,
    const float* __restrict__ Wc1, short* __restrict__ wb)
{
    const int i = blockIdx.x * 256 + threadIdx.x;
    const float* src; int N, n, k, rel;
    if (i < OFF_WE2T)      { rel = i;            src = We1; N = 128; n = rel / 320; k = rel % 320; }
    else if (i < OFF_WN1T) { rel = i - OFF_WE2T; src = We2; N = 128; n = rel / 128; k = rel % 128; }
    else if (i < OFF_WN2T) { rel = i - OFF_WN1T; src = Wn1; N = 128; n = rel / 256; k = rel % 256; }
    else if (i < OFF_WC1T) { rel = i - OFF_WN2T; src = Wn2; N = 128; n = rel / 128; k = rel % 128; }
    else                   { rel = i - OFF_WC1T; src = Wc1; N = 64;  n = rel / 128; k = rel % 128; }
    wb[i] = f2bf(src[(size_t)k * N + n]);
}

// ---------------- edge pipeline (MFMA, barrier-free) ----------------
// 128 edges/block, 4 waves, 32 edges/wave (Mrep=2). B-frags direct from L2.
// All LDS is wave-private (H rows owned by one wave) -> no __syncthreads.
__global__ __launch_bounds__(256, 4) void edge_kernel(
    const float* __restrict__ nf, const float* __restrict__ ea,
    const float* __restrict__ coords, const int* __restrict__ ei,
    const short* __restrict__ wb,
    const float* __restrict__ be1, const float* __restrict__ be2,
    const float* __restrict__ bc1, const float* __restrict__ bc2,
    const float* __restrict__ Wc2f,
    float* __restrict__ aggr, float* __restrict__ coord_acc)
{
    __shared__ int   sS[128], sD[128];
    __shared__ short Hs[128][136];   // bf16 h1/h2, row stride 136 (+pad -> conflict-free b128)

    const int tid   = threadIdx.x;
    const int wv    = tid >> 6;
    const int lane  = tid & 63;
    const int le    = lane & 15;
    const int grp   = lane >> 4;     // 0..3
    const int eb    = blockIdx.x * 128;
    const int wbase = wv * 32;

    // stage this wave's 32 edge indices (wave-private region, same-wave LDS ordering)
    if (lane < 32) sS[wbase + lane] = ei[eb + wbase + lane];
    else           sD[wbase + (lane - 32)] = ei[NE + eb + wbase + (lane - 32)];

    const int srm0 = sS[wbase + le],      srm1 = sS[wbase + 16 + le];
    const int drm0 = sD[wbase + le],      drm1 = sD[wbase + 16 + le];

    // ===== MLP1: h1 = silu(A @ We1 + be1), K=320
    f32x4 acc[2][8];
    #pragma unroll
    for (int m = 0; m < 2; ++m)
        #pragma unroll
        for (int t = 0; t < 8; ++t) acc[m][t] = (f32x4){0.f, 0.f, 0.f, 0.f};

    const short* w1 = wb + OFF_WE1T;
    #pragma unroll
    for (int kc = 0; kc < 10; ++kc) {
        const int gk = kc * 32 + grp * 8;
        short8 a0, a1;
        {
            const float *p0, *p1;
            if (kc < 4)      { p0 = nf + (size_t)srm0 * 128 + gk;       p1 = nf + (size_t)srm1 * 128 + gk; }
            else if (kc < 8) { p0 = nf + (size_t)drm0 * 128 + gk - 128; p1 = nf + (size_t)drm1 * 128 + gk - 128; }
            else             { p0 = ea + (size_t)(eb + wbase + le) * 64 + gk - 256;
                               p1 = ea + (size_t)(eb + wbase + 16 + le) * 64 + gk - 256; }
            a0 = cvt8(*(const float4*)p0, *(const float4*)(p0 + 4));
            a1 = cvt8(*(const float4*)p1, *(const float4*)(p1 + 4));
        }
        #pragma unroll
        for (int th = 0; th < 2; ++th) {
            short8 bf[4];
            #pragma unroll
            for (int t4 = 0; t4 < 4; ++t4)
                bf[t4] = *(const short8*)(w1 + (size_t)((th * 4 + t4) * 16 + le) * 320 + gk);
            #pragma unroll
            for (int t4 = 0; t4 < 4; ++t4) {
                acc[0][th*4+t4] = __builtin_amdgcn_mfma_f32_16x16x32_bf16(a0, bf[t4], acc[0][th*4+t4], 0, 0, 0);
                acc[1][th*4+t4] = __builtin_amdgcn_mfma_f32_16x16x32_bf16(a1, bf[t4], acc[1][th*4+t4], 0, 0, 0);
            }
        }
    }
    // h1 epilogue -> Hs (bf16). C layout: col = le, row = grp*4 + reg (per 16-edge tile m)
    #pragma unroll
    for (int t = 0; t < 8; ++t) {
        const float b1 = be1[t * 16 + le];
        #pragma unroll
        for (int m = 0; m < 2; ++m)
            #pragma unroll
            for (int r = 0; r < 4; ++r)
                Hs[wbase + m * 16 + grp * 4 + r][t * 16 + le] = f2bf(silu_f(acc[m][t][r] + b1));
    }

    // ===== MLP2: h2 = silu(h1 @ We2 + be2), K=128
    f32x4 acc2[2][8];
    #pragma unroll
    for (int m = 0; m < 2; ++m)
        #pragma unroll
        for (int t = 0; t < 8; ++t) acc2[m][t] = (f32x4){0.f, 0.f, 0.f, 0.f};

    const short* w2 = wb + OFF_WE2T;
    #pragma unroll
    for (int kc = 0; kc < 4; ++kc) {
        const int gk = kc * 32 + grp * 8;
        const short8 a0 = *(const short8*)&Hs[wbase + le][gk];
        const short8 a1 = *(const short8*)&Hs[wbase + 16 + le][gk];
        #pragma unroll
        for (int th = 0; th < 2; ++th) {
            short8 bf[4];
            #pragma unroll
            for (int t4 = 0; t4 < 4; ++t4)
                bf[t4] = *(const short8*)(w2 + (size_t)((th * 4 + t4) * 16 + le) * 128 + gk);
            #pragma unroll
            for (int t4 = 0; t4 < 4; ++t4) {
                acc2[0][th*4+t4] = __builtin_amdgcn_mfma_f32_16x16x32_bf16(a0, bf[t4], acc2[0][th*4+t4], 0, 0, 0);
                acc2[1][th*4+t4] = __builtin_amdgcn_mfma_f32_16x16x32_bf16(a1, bf[t4], acc2[1][th*4+t4], 0, 0, 0);
            }
        }
    }

    // h2 epilogue: fp32 atomic scatter (16 consecutive floats per quarter-wave) + Hs overwrite
    int dstv[2][4];
    #pragma unroll
    for (int m = 0; m < 2; ++m)
        #pragma unroll
        for (int r = 0; r < 4; ++r)
            dstv[m][r] = sD[wbase + m * 16 + grp * 4 + r];

    #pragma unroll
    for (int t = 0; t < 8; ++t) {
        const float b2 = be2[t * 16 + le];
        #pragma unroll
        for (int m = 0; m < 2; ++m)
            #pragma unroll
            for (int r = 0; r < 4; ++r) {
                const float v = silu_f(acc2[m][t][r] + b2);
                atomicAdd(&aggr[(size_t)dstv[m][r] * 128 + t * 16 + le], v);
                Hs[wbase + m * 16 + grp * 4 + r][t * 16 + le] = f2bf(v);
            }
    }

    // ===== coord MLP: c1 = silu(h2 @ Wc1 + bc1)  (K=128, N=64)
    f32x4 acc3[2][4];
    #pragma unroll
    for (int m = 0; m < 2; ++m)
        #pragma unroll
        for (int t = 0; t < 4; ++t) acc3[m][t] = (f32x4){0.f, 0.f, 0.f, 0.f};

    const short* wc = wb + OFF_WC1T;
    #pragma unroll
    for (int kc = 0; kc < 4; ++kc) {
        const int gk = kc * 32 + grp * 8;
        const short8 a0 = *(const short8*)&Hs[wbase + le][gk];
        const short8 a1 = *(const short8*)&Hs[wbase + 16 + le][gk];
        short8 bf[4];
        #pragma unroll
        for (int t4 = 0; t4 < 4; ++t4)
            bf[t4] = *(const short8*)(wc + (size_t)(t4 * 16 + le) * 128 + gk);
        #pragma unroll
        for (int t4 = 0; t4 < 4; ++t4) {
            acc3[0][t4] = __builtin_amdgcn_mfma_f32_16x16x32_bf16(a0, bf[t4], acc3[0][t4], 0, 0, 0);
            acc3[1][t4] = __builtin_amdgcn_mfma_f32_16x16x32_bf16(a1, bf[t4], acc3[1][t4], 0, 0, 0);
        }
    }

    // coord_w partials: sum over this lane's 4 col-tiles, then butterfly over le lanes
    float part[2][4];
    #pragma unroll
    for (int m = 0; m < 2; ++m)
        #pragma unroll
        for (int r = 0; r < 4; ++r) part[m][r] = 0.f;
    #pragma unroll
    for (int t = 0; t < 4; ++t) {
        const float bc = bc1[t * 16 + le];
        const float w2c = Wc2f[t * 16 + le];
        #pragma unroll
        for (int m = 0; m < 2; ++m)
            #pragma unroll
            for (int r = 0; r < 4; ++r)
                part[m][r] += silu_f(acc3[m][t][r] + bc) * w2c;
    }
    #pragma unroll
    for (int mask = 1; mask <= 8; mask <<= 1)
        #pragma unroll
        for (int m = 0; m < 2; ++m)
            #pragma unroll
            for (int r = 0; r < 4; ++r)
                part[m][r] += __shfl_xor(part[m][r], mask);

    // owner lanes (le<8): one edge each -> geometry + coord scatter
    if (le < 8) {
        const int m = le >> 2, r = le & 3;
        float v;
        if (m == 0) v = (r == 0) ? part[0][0] : (r == 1) ? part[0][1] : (r == 2) ? part[0][2] : part[0][3];
        else        v = (r == 0) ? part[1][0] : (r == 1) ? part[1][1] : (r == 2) ? part[1][2] : part[1][3];
        const int eloc = wbase + m * 16 + grp * 4 + r;
        const int s = sS[eloc], d = sD[eloc];
        const float dx = coords[3 * s + 0] - coords[3 * d + 0];
        const float dy = coords[3 * s + 1] - coords[3 * d + 1];
        const float dz = coords[3 * s + 2] - coords[3 * d + 2];
        const float wq = v + bc2[0];
        const float inv = wq / (sqrtf(dx * dx + dy * dy + dz * dz) + 1e-8f);
        atomicAdd(&coord_acc[3 * d + 0], dx * inv);
        atomicAdd(&coord_acc[3 * d + 1], dy * inv);
        atomicAdd(&coord_acc[3 * d + 2], dz * inv);
    }
}

// ---------------- node update (MFMA, barrier-free) ----------------
// 128 nodes/block, 4 waves, 32 nodes/wave.
__global__ __launch_bounds__(256, 4) void node_kernel(
    const float* __restrict__ nf, const float* __restrict__ coords,
    const short* __restrict__ wb,
    const float* __restrict__ bn1, const float* __restrict__ bn2,
    const float* __restrict__ aggr, const float* __restrict__ coord_acc,
    float* __restrict__ out)
{
    __shared__ short Hs[128][136];

    const int tid   = threadIdx.x;
    const int wv    = tid >> 6;
    const int lane  = tid & 63;
    const int le    = lane & 15;
    const int grp   = lane >> 4;
    const int nb    = blockIdx.x * 128;
    const int wbase = wv * 32;

    const int row0 = min(nb + wbase + le, NN - 1);
    const int row1 = min(nb + wbase + 16 + le, NN - 1);

    // MLP1: K=256 ([nf | aggr])
    f32x4 acc[2][8];
    #pragma unroll
    for (int m = 0; m < 2; ++m)
        #pragma unroll
        for (int t = 0; t < 8; ++t) acc[m][t] = (f32x4){0.f, 0.f, 0.f, 0.f};

    const short* w1 = wb + OFF_WN1T;
    #pragma unroll
    for (int kc = 0; kc < 8; ++kc) {
        const int gk = kc * 32 + grp * 8;
        const float* p0 = (kc < 4) ? nf + (size_t)row0 * 128 + gk : aggr + (size_t)row0 * 128 + gk - 128;
        const float* p1 = (kc < 4) ? nf + (size_t)row1 * 128 + gk : aggr + (size_t)row1 * 128 + gk - 128;
        const short8 a0 = cvt8(*(const float4*)p0, *(const float4*)(p0 + 4));
        const short8 a1 = cvt8(*(const float4*)p1, *(const float4*)(p1 + 4));
        #pragma unroll
        for (int th = 0; th < 2; ++th) {
            short8 bf[4];
            #pragma unroll
            for (int t4 = 0; t4 < 4; ++t4)
                bf[t4] = *(const short8*)(w1 + (size_t)((th * 4 + t4) * 16 + le) * 256 + gk);
            #pragma unroll
            for (int t4 = 0; t4 < 4; ++t4) {
                acc[0][th*4+t4] = __builtin_amdgcn_mfma_f32_16x16x32_bf16(a0, bf[t4], acc[0][th*4+t4], 0, 0, 0);
                acc[1][th*4+t4] = __builtin_amdgcn_mfma_f32_16x16x32_bf16(a1, bf[t4], acc[1][th*4+t4], 0, 0, 0);
            }
        }
    }
    #pragma unroll
    for (int t = 0; t < 8; ++t) {
        const float b1 = bn1[t * 16 + le];
        #pragma unroll
        for (int m = 0; m < 2; ++m)
            #pragma unroll
            for (int r = 0; r < 4; ++r)
                Hs[wbase + m * 16 + grp * 4 + r][t * 16 + le] = f2bf(silu_f(acc[m][t][r] + b1));
    }

    // MLP2: K=128, then residual
    f32x4 acc2[2][8];
    #pragma unroll
    for (int m = 0; m < 2; ++m)
        #pragma unroll
        for (int t = 0; t < 8; ++t) acc2[m][t] = (f32x4){0.f, 0.f, 0.f, 0.f};

    const short* w2 = wb + OFF_WN2T;
    #pragma unroll
    for (int kc = 0; kc < 4; ++kc) {
        const int gk = kc * 32 + grp * 8;
        const short8 a0 = *(const short8*)&Hs[wbase + le][gk];
        const short8 a1 = *(const short8*)&Hs[wbase + 16 + le][gk];
        #pragma unroll
        for (int th = 0; th < 2; ++th) {
            short8 bf[4];
            #pragma unroll
            for (int t4 = 0; t4 < 4; ++t4)
                bf[t4] = *(const short8*)(w2 + (size_t)((th * 4 + t4) * 16 + le) * 128 + gk);
            #pragma unroll
            for (int t4 = 0; t4 < 4; ++t4) {
                acc2[0][th*4+t4] = __builtin_amdgcn_mfma_f32_16x16x32_bf16(a0, bf[t4], acc2[0][th*4+t4], 0, 0, 0);
                acc2[1][th*4+t4] = __builtin_amdgcn_mfma_f32_16x16x32_bf16(a1, bf[t4], acc2[1][th*4+t4], 0, 0, 0);
            }
        }
    }
    #pragma unroll
    for (int t = 0; t < 8; ++t) {
        const float b2 = bn2[t * 16 + le];
        #pragma unroll
        for (int m = 0; m < 2; ++m)
            #pragma unroll
            for (int r = 0; r < 4; ++r) {
                const int row = nb + wbase + m * 16 + grp * 4 + r;
                if (row < NN) {
                    const int c = t * 16 + le;
                    out[(size_t)row * 128 + c] = acc2[m][t][r] + b2 + nf[(size_t)row * 128 + c];
                }
            }
    }

    // coords epilogue: 128 nodes * 3
    for (int i = tid; i < 384; i += 256) {
        const int n = nb + i / 3, j = i % 3;
        if (n < NN)
            out[(size_t)NN * 128 + 3 * n + j] = coords[3 * n + j] + coord_acc[3 * n + j];
    }
}

extern "C" void kernel_launch(void* const* d_in, const int* in_sizes, int n_in,
                              void* d_out, int out_size, void* d_ws, size_t ws_size,
                              hipStream_t stream)
{
    const float* node_feat  = (const float*)d_in[0];
    const float* edge_attr  = (const float*)d_in[1];
    const float* coords     = (const float*)d_in[2];
    const int*   edge_index = (const int*)d_in[3];
    const float* We1 = (const float*)d_in[4];
    const float* be1 = (const float*)d_in[5];
    const float* We2 = (const float*)d_in[6];
    const float* be2 = (const float*)d_in[7];
    const float* Wn1 = (const float*)d_in[8];
    const float* bn1 = (const float*)d_in[9];
    const float* Wn2 = (const float*)d_in[10];
    const float* bn2 = (const float*)d_in[11];
    const float* Wc1 = (const float*)d_in[12];
    const float* bc1 = (const float*)d_in[13];
    const float* Wc2 = (const float*)d_in[14];
    const float* bc2 = (const float*)d_in[15];

    float* out       = (float*)d_out;
    float* aggr      = (float*)d_ws;                          // [NN,128] f32
    float* coord_acc = aggr + (size_t)NN * 128;               // [NN,3]   f32
    short* wbf       = (short*)(coord_acc + (size_t)NN * 3);  // bf16 weights (229 KB)

    prep_kernel<<<W_TOTAL / 256, 256, 0, stream>>>(We1, We2, Wn1, Wn2, Wc1, wbf);

    const int n4 = (NN * 128 + NN * 3) / 4;   // re-zero accumulators every call
    zero_kernel<<<2048, 256, 0, stream>>>((float4*)d_ws, n4);

    edge_kernel<<<NE / 128, 256, 0, stream>>>(
        node_feat, edge_attr, coords, edge_index, wbf,
        be1, be2, bc1, bc2, Wc2, aggr, coord_acc);

    node_kernel<<<(NN + 127) / 128, 256, 0, stream>>>(
        node_feat, coords, wbf, bn1, bn2, aggr, coord_acc, out);
}